// Round 1
// baseline (31.823 us; speedup 1.0000x reference)
//
#include <hip/hip_runtime.h>
#include <hip/hip_bf16.h>
#include <math.h>

// PyramidROIAlign: boxes [B*N,4] (y1,x1,y2,x2 normalized), 4 FPN levels
// P2..P5 with H=W=256,128,64,32, C=256. Output [B*N,7,7,256] fp32.
// One thread handles 4 consecutive channels at one (box, py, px) position.

#define CCH 256       // channels
#define PH 7
#define PW 7

__global__ __launch_bounds__(256) void PyramidROIAlign_kernel(
    const float* __restrict__ boxes,   // [TB,4]
    const float* __restrict__ meta,    // [B,93]
    const float* __restrict__ P2,
    const float* __restrict__ P3,
    const float* __restrict__ P4,
    const float* __restrict__ P5,
    float* __restrict__ out,           // [TB,7,7,C]
    int total_boxes,
    int n_per_batch)
{
    int idx = blockIdx.x * blockDim.x + threadIdx.x;
    int c4 = (idx & 63) << 2;          // channel group (4 channels)
    int p  = idx >> 6;                 // (box, py, px) position
    if (p >= total_boxes * (PH * PW)) return;

    int n  = p / (PH * PW);
    int r  = p - n * (PH * PW);
    int py = r / PW;
    int px = r - py * PW;

    // box params
    float y1 = boxes[n * 4 + 0];
    float x1 = boxes[n * 4 + 1];
    float y2 = boxes[n * 4 + 2];
    float x2 = boxes[n * 4 + 3];
    float h = y2 - y1;
    float w = x2 - x1;

    // level selection (replicate reference op order)
    float area  = meta[4] * meta[5];
    float scale = 224.0f / sqrtf(area);
    float lvlf  = log2f(sqrtf(h * w) / scale);
    int level = 4 + (int)rintf(lvlf);          // rintf = round half-to-even
    level = min(max(level, 2), 5);

    const float* fmap;
    int H;
    switch (level) {
        case 2:  fmap = P2; H = 256; break;
        case 3:  fmap = P3; H = 128; break;
        case 4:  fmap = P4; H = 64;  break;
        default: fmap = P5; H = 32;  break;
    }
    int W = H;
    // batch offset (B==1 in practice; n_per_batch = TB/B)
    int b = n / n_per_batch;
    fmap += (size_t)b * H * W * CCH;

    // bilinear coordinates (reference op order: (y1 + ty*(y2-y1)) * (H-1))
    float ty = (float)py / (float)(PH - 1);
    float tx = (float)px / (float)(PW - 1);
    float ys = (y1 + ty * (y2 - y1)) * (float)(H - 1);
    float xs = (x1 + tx * (x2 - x1)) * (float)(W - 1);

    float y0f = fminf(fmaxf(floorf(ys), 0.0f), (float)(H - 1));
    float x0f = fminf(fmaxf(floorf(xs), 0.0f), (float)(W - 1));
    int y0 = (int)y0f;
    int x0 = (int)x0f;
    int y1i = min(y0 + 1, H - 1);
    int x1i = min(x0 + 1, W - 1);
    float wy = ys - y0f;
    float wx = xs - x0f;

    const float4* r00 = (const float4*)(fmap + ((size_t)y0  * W + x0 ) * CCH + c4);
    const float4* r01 = (const float4*)(fmap + ((size_t)y0  * W + x1i) * CCH + c4);
    const float4* r10 = (const float4*)(fmap + ((size_t)y1i * W + x0 ) * CCH + c4);
    const float4* r11 = (const float4*)(fmap + ((size_t)y1i * W + x1i) * CCH + c4);

    float4 v00 = *r00;
    float4 v01 = *r01;
    float4 v10 = *r10;
    float4 v11 = *r11;

    float4 o;
    {
        float top = v00.x + (v01.x - v00.x) * wx;
        float bot = v10.x + (v11.x - v10.x) * wx;
        o.x = top + (bot - top) * wy;
        top = v00.y + (v01.y - v00.y) * wx;
        bot = v10.y + (v11.y - v10.y) * wx;
        o.y = top + (bot - top) * wy;
        top = v00.z + (v01.z - v00.z) * wx;
        bot = v10.z + (v11.z - v10.z) * wx;
        o.z = top + (bot - top) * wy;
        top = v00.w + (v01.w - v00.w) * wx;
        bot = v10.w + (v11.w - v10.w) * wx;
        o.w = top + (bot - top) * wy;
    }

    *((float4*)(out + (size_t)p * CCH + c4)) = o;
}

extern "C" void kernel_launch(void* const* d_in, const int* in_sizes, int n_in,
                              void* d_out, int out_size, void* d_ws, size_t ws_size,
                              hipStream_t stream) {
    const float* boxes = (const float*)d_in[0];   // [B,N,4]
    const float* meta  = (const float*)d_in[1];   // [B,93]
    const float* P2    = (const float*)d_in[2];
    const float* P3    = (const float*)d_in[3];
    const float* P4    = (const float*)d_in[4];
    const float* P5    = (const float*)d_in[5];
    float* out = (float*)d_out;

    int total_boxes = in_sizes[0] / 4;            // B*N
    int B = in_sizes[1] / 93;
    if (B < 1) B = 1;
    int n_per_batch = total_boxes / B;

    long total_threads = (long)total_boxes * (PH * PW) * 64;
    int threads = 256;
    int blocks = (int)((total_threads + threads - 1) / threads);

    PyramidROIAlign_kernel<<<blocks, threads, 0, stream>>>(
        boxes, meta, P2, P3, P4, P5, out, total_boxes, n_per_batch);
}

// Round 2
// 29.760 us; speedup vs baseline: 1.0693x; 1.0693x over previous
//
#include <hip/hip_runtime.h>
#include <hip/hip_bf16.h>
#include <math.h>

// PyramidROIAlign: one WAVE per (box, py) row. 64 lanes x 4 channels = 256 ch.
// Each wave loops over the 7 px positions (unrolled). Box-level math (level
// selection, y-interp, row pointers) computed once per wave, scalarized via
// readfirstlane.

#define CCH 256
#define PH 7
#define PW 7

__global__ __launch_bounds__(256) void PyramidROIAlign_kernel(
    const float* __restrict__ boxes,   // [TB,4]
    const float* __restrict__ meta,    // [B,93]
    const float* __restrict__ P2,
    const float* __restrict__ P3,
    const float* __restrict__ P4,
    const float* __restrict__ P5,
    float* __restrict__ out,           // [TB,7,7,C]
    int total_boxes,
    int n_per_batch)
{
    int wid  = (blockIdx.x * blockDim.x + threadIdx.x) >> 6;
    int lane = threadIdx.x & 63;
    if (wid >= total_boxes * PH) return;
    wid = __builtin_amdgcn_readfirstlane(wid);   // wave-uniform -> SGPR math

    int n  = wid / PH;
    int py = wid - n * PH;

    float y1 = boxes[n * 4 + 0];
    float x1 = boxes[n * 4 + 1];
    float y2 = boxes[n * 4 + 2];
    float x2 = boxes[n * 4 + 3];

    // level selection (reference op order; rintf = round half-even like jnp.round)
    float area  = meta[4] * meta[5];
    float scale = 224.0f / sqrtf(area);
    float lvlf  = log2f(sqrtf((y2 - y1) * (x2 - x1)) / scale);
    int level = 4 + (int)rintf(lvlf);
    level = min(max(level, 2), 5);

    const float* fmap;
    int H;
    switch (level) {
        case 2:  fmap = P2; H = 256; break;
        case 3:  fmap = P3; H = 128; break;
        case 4:  fmap = P4; H = 64;  break;
        default: fmap = P5; H = 32;  break;
    }
    int W = H;
    int b = n / n_per_batch;                 // B==1 normally
    fmap += (size_t)b * H * W * CCH;

    // y interpolation — once per wave
    float ty  = (float)py / (float)(PH - 1);
    float ys  = (y1 + ty * (y2 - y1)) * (float)(H - 1);
    float y0f = fminf(fmaxf(floorf(ys), 0.0f), (float)(H - 1));
    int   y0  = (int)y0f;
    int   y1r = min(y0 + 1, H - 1);
    float wy  = ys - y0f;

    const float* row0 = fmap + (size_t)y0  * W * CCH;
    const float* row1 = fmap + (size_t)y1r * W * CCH;

    int c = lane << 2;                       // 4 consecutive channels per lane
    float* optr = out + ((size_t)wid * PW) * CCH + c;

    #pragma unroll
    for (int px = 0; px < PW; ++px) {
        float tx  = (float)px / (float)(PW - 1);   // constant-folded after unroll
        float xs  = (x1 + tx * (x2 - x1)) * (float)(W - 1);
        float x0f = fminf(fmaxf(floorf(xs), 0.0f), (float)(W - 1));
        int   x0  = (int)x0f;
        int   x1r = min(x0 + 1, W - 1);
        float wx  = xs - x0f;

        int o0 = x0  * CCH + c;
        int o1 = x1r * CCH + c;
        float4 v00 = *(const float4*)(row0 + o0);
        float4 v01 = *(const float4*)(row0 + o1);
        float4 v10 = *(const float4*)(row1 + o0);
        float4 v11 = *(const float4*)(row1 + o1);

        float4 o;
        float top, bot;
        top = v00.x + (v01.x - v00.x) * wx;
        bot = v10.x + (v11.x - v10.x) * wx;
        o.x = top + (bot - top) * wy;
        top = v00.y + (v01.y - v00.y) * wx;
        bot = v10.y + (v11.y - v10.y) * wx;
        o.y = top + (bot - top) * wy;
        top = v00.z + (v01.z - v00.z) * wx;
        bot = v10.z + (v11.z - v10.z) * wx;
        o.z = top + (bot - top) * wy;
        top = v00.w + (v01.w - v00.w) * wx;
        bot = v10.w + (v11.w - v10.w) * wx;
        o.w = top + (bot - top) * wy;

        *((float4*)(optr + px * CCH)) = o;
    }
}

extern "C" void kernel_launch(void* const* d_in, const int* in_sizes, int n_in,
                              void* d_out, int out_size, void* d_ws, size_t ws_size,
                              hipStream_t stream) {
    const float* boxes = (const float*)d_in[0];   // [B,N,4]
    const float* meta  = (const float*)d_in[1];   // [B,93]
    const float* P2    = (const float*)d_in[2];
    const float* P3    = (const float*)d_in[3];
    const float* P4    = (const float*)d_in[4];
    const float* P5    = (const float*)d_in[5];
    float* out = (float*)d_out;

    int total_boxes = in_sizes[0] / 4;            // B*N
    int B = in_sizes[1] / 93;
    if (B < 1) B = 1;
    int n_per_batch = total_boxes / B;

    long total_threads = (long)total_boxes * PH * 64;   // one wave per (box,py)
    int threads = 256;
    int blocks = (int)((total_threads + threads - 1) / threads);

    PyramidROIAlign_kernel<<<blocks, threads, 0, stream>>>(
        boxes, meta, P2, P3, P4, P5, out, total_boxes, n_per_batch);
}

// Round 3
// 29.424 us; speedup vs baseline: 1.0815x; 1.0114x over previous
//
#include <hip/hip_runtime.h>
#include <hip/hip_bf16.h>
#include <math.h>

// PyramidROIAlign: one WAVE per (box, py) row. 64 lanes x 4 channels.
// Software-pipelined px loop (prefetch next 4 corners while interpolating
// current), launch_bounds(256,4) to keep >=4 waves/SIMD, XCD-chunked block
// swizzle for per-box L2 locality.

#define CCH 256
#define PH 7
#define PW 7
#define NXCD 8

__global__ __launch_bounds__(256, 4) void PyramidROIAlign_kernel(
    const float* __restrict__ boxes,   // [TB,4]
    const float* __restrict__ meta,    // [B,93]
    const float* __restrict__ P2,
    const float* __restrict__ P3,
    const float* __restrict__ P4,
    const float* __restrict__ P5,
    float* __restrict__ out,           // [TB,7,7,C]
    int total_boxes,
    int n_per_batch)
{
    // bijective XCD-chunk remap of blockIdx so consecutive remapped blocks
    // (same box) land on the same XCD's L2.
    int nwg = gridDim.x;
    int q = nwg / NXCD, r = nwg % NXCD;
    int xcd = blockIdx.x % NXCD;
    int off = blockIdx.x / NXCD;
    int bid = (xcd < r ? xcd * (q + 1) : r * (q + 1) + (xcd - r) * q) + off;

    int wid  = bid * (256 / 64) + (threadIdx.x >> 6);
    int lane = threadIdx.x & 63;
    if (wid >= total_boxes * PH) return;
    wid = __builtin_amdgcn_readfirstlane(wid);

    int n  = wid / PH;
    int py = wid - n * PH;

    float y1 = boxes[n * 4 + 0];
    float x1 = boxes[n * 4 + 1];
    float y2 = boxes[n * 4 + 2];
    float x2 = boxes[n * 4 + 3];

    // level selection (reference op order; rintf = round-half-even)
    float area  = meta[4] * meta[5];
    float scale = 224.0f / sqrtf(area);
    float lvlf  = log2f(sqrtf((y2 - y1) * (x2 - x1)) / scale);
    int level = 4 + (int)rintf(lvlf);
    level = min(max(level, 2), 5);

    const float* fmap;
    int H;
    switch (level) {
        case 2:  fmap = P2; H = 256; break;
        case 3:  fmap = P3; H = 128; break;
        case 4:  fmap = P4; H = 64;  break;
        default: fmap = P5; H = 32;  break;
    }
    int W = H;
    int b = n / n_per_batch;
    fmap += (size_t)b * H * W * CCH;

    // y interpolation — once per wave
    float ty  = (float)py / (float)(PH - 1);
    float ys  = (y1 + ty * (y2 - y1)) * (float)(H - 1);
    float y0f = fminf(fmaxf(floorf(ys), 0.0f), (float)(H - 1));
    int   y0  = (int)y0f;
    int   y1r = min(y0 + 1, H - 1);
    float wy  = ys - y0f;

    int c = lane << 2;
    const float* row0 = fmap + (size_t)y0  * W * CCH + c;
    const float* row1 = fmap + (size_t)y1r * W * CCH + c;

    // precompute all px offsets/weights (registers after full unroll)
    int   o0[PW], o1[PW];
    float wxv[PW];
    #pragma unroll
    for (int px = 0; px < PW; ++px) {
        float tx  = (float)px / (float)(PW - 1);
        float xs  = (x1 + tx * (x2 - x1)) * (float)(W - 1);
        float x0f = fminf(fmaxf(floorf(xs), 0.0f), (float)(W - 1));
        int   x0  = (int)x0f;
        int   x1c = min(x0 + 1, W - 1);
        wxv[px] = xs - x0f;
        o0[px] = x0  * CCH;
        o1[px] = x1c * CCH;
    }

    float* optr = out + ((size_t)wid * PW) * CCH + c;

    // software pipeline: prefetch next px's 4 corners while computing current
    float4 a00 = *(const float4*)(row0 + o0[0]);
    float4 a01 = *(const float4*)(row0 + o1[0]);
    float4 a10 = *(const float4*)(row1 + o0[0]);
    float4 a11 = *(const float4*)(row1 + o1[0]);

    #pragma unroll
    for (int px = 0; px < PW; ++px) {
        float4 b00, b01, b10, b11;
        if (px + 1 < PW) {
            b00 = *(const float4*)(row0 + o0[px + 1]);
            b01 = *(const float4*)(row0 + o1[px + 1]);
            b10 = *(const float4*)(row1 + o0[px + 1]);
            b11 = *(const float4*)(row1 + o1[px + 1]);
        }
        float wx = wxv[px];
        float4 o;
        float top, bot;
        top = a00.x + (a01.x - a00.x) * wx;
        bot = a10.x + (a11.x - a10.x) * wx;
        o.x = top + (bot - top) * wy;
        top = a00.y + (a01.y - a00.y) * wx;
        bot = a10.y + (a11.y - a10.y) * wx;
        o.y = top + (bot - top) * wy;
        top = a00.z + (a01.z - a00.z) * wx;
        bot = a10.z + (a11.z - a10.z) * wx;
        o.z = top + (bot - top) * wy;
        top = a00.w + (a01.w - a00.w) * wx;
        bot = a10.w + (a11.w - a10.w) * wx;
        o.w = top + (bot - top) * wy;

        *((float4*)(optr + px * CCH)) = o;

        a00 = b00; a01 = b01; a10 = b10; a11 = b11;
    }
}

extern "C" void kernel_launch(void* const* d_in, const int* in_sizes, int n_in,
                              void* d_out, int out_size, void* d_ws, size_t ws_size,
                              hipStream_t stream) {
    const float* boxes = (const float*)d_in[0];   // [B,N,4]
    const float* meta  = (const float*)d_in[1];   // [B,93]
    const float* P2    = (const float*)d_in[2];
    const float* P3    = (const float*)d_in[3];
    const float* P4    = (const float*)d_in[4];
    const float* P5    = (const float*)d_in[5];
    float* out = (float*)d_out;

    int total_boxes = in_sizes[0] / 4;            // B*N
    int B = in_sizes[1] / 93;
    if (B < 1) B = 1;
    int n_per_batch = total_boxes / B;

    long total_waves = (long)total_boxes * PH;    // one wave per (box,py)
    int blocks = (int)((total_waves + 3) / 4);    // 4 waves per block

    PyramidROIAlign_kernel<<<blocks, 256, 0, stream>>>(
        boxes, meta, P2, P3, P4, P5, out, total_boxes, n_per_batch);
}